// Round 1
// baseline (595.805 us; speedup 1.0000x reference)
//
#include <hip/hip_runtime.h>

// Com2Net wavefront kernel, round 4.
// Schedule s = 2t + i; one wave per run, lane j owns agents {2j, 2j+1}.
// Issue-bound on a single SIMD (VALUBusy 10.2% vs 12.5% structural cap
// = 82% issue occupancy). This round:
//   - sigma-fold: W2@tanh = (W2@1 + b2) + (-2*W2)@sigma, sigma = rcp(1+e^{2y}).
//     Deletes the per-element (1 - 2r) glue fma: -5 pk_fma per eval.
//   - x-part software pipelining: layer-1 (xa,xb,b1) preacts are recurrence-
//     independent -> computed at the distance-4 prefetch slot, parking ~80
//     cyc/step of independent work to fill the even->odd->even chain stalls.
//   - int clamp via min/max (2 ops) instead of nested selects.
// Numerics: no reassociation of rcp or dot chains (absmax budget is tight).

#define T_STEPS 1024
#define N_AGENTS 128

typedef float v2f __attribute__((ext_vector_type(2)));

__device__ __forceinline__ v2f sp(float x) { return (v2f){x, x}; }

// Whole-wave shift-by-1 via DPP. wave_shr1 (0x138): lane i <- lane i-1,
// lane 0 <- 0 (bound_ctrl). wave_shl1 (0x130): lane i <- lane i+1, lane 63 <- 0.
__device__ __forceinline__ float wave_shr1(float x) {
    int r = __builtin_amdgcn_update_dpp(0, __builtin_bit_cast(int, x),
                                        0x138, 0xF, 0xF, true);
    return __builtin_bit_cast(float, r);
}
__device__ __forceinline__ float wave_shl1(float x) {
    int r = __builtin_amdgcn_update_dpp(0, __builtin_bit_cast(int, x),
                                        0x130, 0xF, 0xF, true);
    return __builtin_bit_cast(float, r);
}

struct Weights {
    v2f w1x0[5], w1x1[5];    // layer-1 x weights (cols 0,1), * 2*log2(e)
    v2f w1cA[5], w1cB[5];    // layer-1 comm weights (cols 2,3), * 2*log2(e)
    v2f b1[5];               // * 2*log2(e)
    v2f w20[5], w21[5], w22[5];  // = -2 * W2 row r, packed over hidden pairs
    float b20, b21, b22;         // = b2[r] + sum_k W2[r,k]
};

// Recurrence-independent part of the layer-1 preacts for one row (both agents).
struct XPre { v2f ae[5], ao[5]; };

__device__ __forceinline__ XPre xpart(const Weights& w, const float4& x) {
    XPre r;
#pragma unroll
    for (int p = 0; p < 5; ++p) {
        r.ae[p] = __builtin_elementwise_fma(w.w1x0[p], sp(x.x), w.b1[p]);
        r.ae[p] = __builtin_elementwise_fma(w.w1x1[p], sp(x.y), r.ae[p]);
        r.ao[p] = __builtin_elementwise_fma(w.w1x0[p], sp(x.z), w.b1[p]);
        r.ao[p] = __builtin_elementwise_fma(w.w1x1[p], sp(x.w), r.ao[p]);
    }
    return r;
}

// Recurrence part of one S2Net eval. cA/cB are the chain-late operands ->
// consumed by the last preact fmas. h = sigma = rcp(1 + exp2(a)); the tanh
// affine (1-2*sigma) is folded into w2*/b2* by the caller's weight prep.
__device__ __forceinline__ void mlp_c(const Weights& w, const v2f* ax,
                                      float cA, float cB,
                                      float& o0, float& o1, float& o2) {
    v2f h[5];
#pragma unroll
    for (int p = 0; p < 5; ++p) {
        v2f a = __builtin_elementwise_fma(w.w1cB[p], sp(cB), ax[p]);
        a = __builtin_elementwise_fma(w.w1cA[p], sp(cA), a);
        v2f t;
        t.x = __builtin_amdgcn_exp2f(a.x);
        t.y = __builtin_amdgcn_exp2f(a.y);
        t = t + (v2f){1.f, 1.f};
        h[p].x = __builtin_amdgcn_rcpf(t.x);
        h[p].y = __builtin_amdgcn_rcpf(t.y);
    }
    // Output dots packed over hidden dim; horizontal add folds the pair.
    // Kept as plain 5-deep fma chains (no reassociation -> stable numerics).
    v2f a0 = __builtin_elementwise_fma(w.w20[0], h[0], (v2f){w.b20, 0.f});
    v2f a1 = __builtin_elementwise_fma(w.w21[0], h[0], (v2f){w.b21, 0.f});
    v2f a2 = __builtin_elementwise_fma(w.w22[0], h[0], (v2f){w.b22, 0.f});
#pragma unroll
    for (int p = 1; p < 5; ++p) {
        a0 = __builtin_elementwise_fma(w.w20[p], h[p], a0);
        a1 = __builtin_elementwise_fma(w.w21[p], h[p], a1);
        a2 = __builtin_elementwise_fma(w.w22[p], h[p], a2);
    }
    o0 = a0.x + a0.y;
    o1 = a1.x + a1.y;
    o2 = a2.x + a2.y;
}

__global__ void __launch_bounds__(64, 1)
com2net_wavefront(const float* __restrict__ runs,
                  const float* __restrict__ W1, const float* __restrict__ b1,
                  const float* __restrict__ W2, const float* __restrict__ b2,
                  float* __restrict__ out)
{
    const int r = blockIdx.x;   // run index
    const int j = threadIdx.x;  // lane 0..63, owns agents 2j and 2j+1

    const float S = 2.8853900817779268f;  // 2*log2(e), folded into layer 1
    Weights w;
#pragma unroll
    for (int p = 0; p < 5; ++p) {
        w.b1[p]   = (v2f){b1[2 * p] * S, b1[2 * p + 1] * S};
        w.w1x0[p] = (v2f){W1[(2 * p) * 4 + 0] * S, W1[(2 * p + 1) * 4 + 0] * S};
        w.w1x1[p] = (v2f){W1[(2 * p) * 4 + 1] * S, W1[(2 * p + 1) * 4 + 1] * S};
        w.w1cA[p] = (v2f){W1[(2 * p) * 4 + 2] * S, W1[(2 * p + 1) * 4 + 2] * S};
        w.w1cB[p] = (v2f){W1[(2 * p) * 4 + 3] * S, W1[(2 * p + 1) * 4 + 3] * S};
        w.w20[p] = (v2f){-2.f * W2[0 * 10 + 2 * p], -2.f * W2[0 * 10 + 2 * p + 1]};
        w.w21[p] = (v2f){-2.f * W2[1 * 10 + 2 * p], -2.f * W2[1 * 10 + 2 * p + 1]};
        w.w22[p] = (v2f){-2.f * W2[2 * 10 + 2 * p], -2.f * W2[2 * 10 + 2 * p + 1]};
    }
    float s0 = 0.f, s1 = 0.f, s2 = 0.f;
#pragma unroll
    for (int k = 0; k < 10; ++k) {
        s0 += W2[0 * 10 + k];
        s1 += W2[1 * 10 + k];
        s2 += W2[2 * 10 + k];
    }
    w.b20 = b2[0] + s0; w.b21 = b2[1] + s1; w.b22 = b2[2] + s2;

    const float4* __restrict__ xbase =
        (const float4*)(runs + (size_t)r * T_STEPS * N_AGENTS * 2);
    float2* __restrict__ obase =
        (float2*)(out + (size_t)r * T_STEPS * N_AGENTS);

    // c1*/c2* = out1/out2 of this lane's even/odd agent at its latest t.
    // Zero-init == initial comm; inactive lanes never update -> t<0 boundary.
    float c1e = 0.f, c2e = 0.f, c1o = 0.f, c2o = 0.f;

    // Clamped row load (OOB lanes re-read row 0/1023; results are discarded
    // by the activity selects, loads hit cache).
    auto ldrow = [&](int t) -> float4 {
        int tc = t < 0 ? 0 : t;
        tc = tc > T_STEPS - 1 ? T_STEPS - 1 : tc;
        return xbase[tc * (N_AGENTS / 2) + j];
    };

    // Serial (recurrence) part of one macro step; x-preacts come in precomputed.
    auto cstep = [&](int u, const XPre& ax) {
        const int t = u - j;
        const bool active = (unsigned)t < (unsigned)T_STEPS;

        // ---- even phase: agent 2j at t ----
        // comm[4j]   = lane j-1's c2o (prev macro-step) -> wave_shr1
        // comm[4j+3] = own c1o (prev macro-step)
        float c2pv = wave_shr1(c2o);
        float o0e, o1e, o2e;
        mlp_c(w, ax.ae, c2pv, c1o, o0e, o1e, o2e);
        c1e = active ? o1e : c1e;
        c2e = active ? o2e : c2e;

        // ---- odd phase: agent 2j+1 at t ----
        // comm[4j+2] = own c2e (just computed)
        // comm[4j+5] = lane j+1's c1e (its even phase this step ran at t-1)
        float c1pv = wave_shl1(c1e);
        float o0o, o1o, o2o;
        mlp_c(w, ax.ao, c2e, c1pv, o0o, o1o, o2o);
        c1o = active ? o1o : c1o;
        c2o = active ? o2o : c2o;

        if (active) obase[t * (N_AGENTS / 2) + j] = make_float2(o0e, o0o);
    };

    // Two-level pipeline: rows prefetched at distance 4-8; x-preacts computed
    // at distance 0-4 (right when the row lands), consumed by the serial step.
    XPre A0 = xpart(w, ldrow(0 - j));
    XPre A1 = xpart(w, ldrow(1 - j));
    XPre A2 = xpart(w, ldrow(2 - j));
    XPre A3 = xpart(w, ldrow(3 - j));
    float4 X0 = ldrow(4 - j);
    float4 X1 = ldrow(5 - j);
    float4 X2 = ldrow(6 - j);
    float4 X3 = ldrow(7 - j);

    for (int u = 0; u < T_STEPS + 64; u += 4) {   // 1088 = 4*272 iters
        cstep(u + 0, A0); A0 = xpart(w, X0); X0 = ldrow(u + 8 - j);
        cstep(u + 1, A1); A1 = xpart(w, X1); X1 = ldrow(u + 9 - j);
        cstep(u + 2, A2); A2 = xpart(w, X2); X2 = ldrow(u + 10 - j);
        cstep(u + 3, A3); A3 = xpart(w, X3); X3 = ldrow(u + 11 - j);
    }
}

extern "C" void kernel_launch(void* const* d_in, const int* in_sizes, int n_in,
                              void* d_out, int out_size, void* d_ws, size_t ws_size,
                              hipStream_t stream) {
    const float* runs = (const float*)d_in[0];
    const float* W1   = (const float*)d_in[1];
    const float* b1   = (const float*)d_in[2];
    const float* W2   = (const float*)d_in[3];
    const float* b2   = (const float*)d_in[4];
    float* out = (float*)d_out;

    const int R = 128;
    com2net_wavefront<<<R, 64, 0, stream>>>(runs, W1, b1, W2, b2, out);
}